// Round 1
// baseline (359.086 us; speedup 1.0000x reference)
//
#include <hip/hip_runtime.h>
#include <cstdint>

typedef __attribute__((ext_vector_type(4))) float f32x4;

// ---------------------------------------------------------------------------
// Kernel 1: block-64 Hadamard rotate (FWHT) + per-row absmax fp8-e4m3fn quant
// One wave per row. Row length K=1024 = 16 blocks of 64.
// lane holds element (lane) of each of the 16 blocks -> FWHT via shfl_xor.
// Transpose through padded LDS so each lane stores 16 contiguous fp8 bytes.
// ---------------------------------------------------------------------------

#define KDIM 1024
#define NBLK 16  // KDIM / 64

__global__ __launch_bounds__(256) void hq_quant_kernel(
    const float* __restrict__ x, const float* __restrict__ w,
    uint8_t* __restrict__ xq, uint8_t* __restrict__ wq,
    float* __restrict__ xs, float* __restrict__ wsc, int mrows, int nrows) {
  // padded layout: float column c stored at c + 4*(c>>4)  (max 1275 -> 1280)
  __shared__ float lds[4][1280];
  const int lane = threadIdx.x & 63;
  const int wave = threadIdx.x >> 6;
  const int gwave = (blockIdx.x * blockDim.x + threadIdx.x) >> 6;
  const int wstride = (gridDim.x * blockDim.x) >> 6;
  const int total = mrows + nrows;
  float* L = lds[wave];

  for (int r = gwave; r < total; r += wstride) {
    const float* src = (r < mrows) ? (x + (size_t)r * KDIM)
                                   : (w + (size_t)(r - mrows) * KDIM);
    uint8_t* dst = (r < mrows) ? (xq + (size_t)r * KDIM)
                               : (wq + (size_t)(r - mrows) * KDIM);
    float* sdst = (r < mrows) ? (xs + r) : (wsc + (r - mrows));

    float v[NBLK];
#pragma unroll
    for (int b = 0; b < NBLK; ++b) v[b] = src[b * 64 + lane];

    // FWHT across the 64 lanes (Sylvester Hadamard: H[i][j] = (-1)^popc(i&j))
#pragma unroll
    for (int s = 1; s < 64; s <<= 1) {
#pragma unroll
      for (int b = 0; b < NBLK; ++b) {
        float o = __shfl_xor(v[b], s, 64);
        v[b] = (lane & s) ? (o - v[b]) : (v[b] + o);
      }
    }

    float amax = 0.f;
#pragma unroll
    for (int b = 0; b < NBLK; ++b) {
      v[b] *= 0.125f;  // 1/sqrt(64), exact
      amax = fmaxf(amax, fabsf(v[b]));
    }
#pragma unroll
    for (int s = 32; s >= 1; s >>= 1) amax = fmaxf(amax, __shfl_xor(amax, s, 64));

    float scale = fmaxf(amax / 448.0f, 1e-12f);  // true IEEE div (448 not pow2)

    // transpose: write column c = b*64+lane at padded address
#pragma unroll
    for (int b = 0; b < NBLK; ++b) {
      int c = b * 64 + lane;
      L[c + 4 * (c >> 4)] = v[b];
    }
    __builtin_amdgcn_wave_barrier();  // DS pipe is in-order per wave; fence compiler

    // read 16 contiguous columns (16l..16l+15) -> padded base = 20*l (16B aligned)
    uint32_t pk[4];
#pragma unroll
    for (int g = 0; g < 4; ++g) {
      f32x4 f = *reinterpret_cast<const f32x4*>(&L[20 * lane + 4 * g]);
      float q0 = f[0] / scale, q1 = f[1] / scale;
      float q2 = f[2] / scale, q3 = f[3] / scale;
      int p = __builtin_amdgcn_cvt_pk_fp8_f32(q0, q1, 0, false);
      p = __builtin_amdgcn_cvt_pk_fp8_f32(q2, q3, p, true);
      pk[g] = (uint32_t)p;
    }
    *reinterpret_cast<uint4*>(dst + lane * 16) =
        make_uint4(pk[0], pk[1], pk[2], pk[3]);
    if (lane == 0) *sdst = scale;
    __builtin_amdgcn_wave_barrier();  // don't overwrite L before reads done (in-order anyway)
  }
}

// ---------------------------------------------------------------------------
// Kernel 2: fp8 GEMM  C[M,N] = (Aq[M,K] . Bq[N,K]^T) * as[m] * bs[n] + bias[n]
// m97 structure: 128x128 tile, BK=64, 4 waves (2x2 of 64x64), global_load_lds
// width=16, mfma_f32_16x16x32_fp8_fp8.
// ---------------------------------------------------------------------------

__device__ __forceinline__ void gload16(const uint8_t* g, uint8_t* l) {
  __builtin_amdgcn_global_load_lds(
      (const __attribute__((address_space(1))) void*)g,
      (__attribute__((address_space(3))) void*)l, 16, 0, 0);
}

__global__ __launch_bounds__(256) void hq_gemm_kernel(
    const uint8_t* __restrict__ Aq, const uint8_t* __restrict__ Bq,
    const float* __restrict__ As, const float* __restrict__ Bs,
    const float* __restrict__ bias, float* __restrict__ C, int M, int N,
    int Kd) {
  constexpr int BM = 128, BN = 128, BK = 64;
  __shared__ uint8_t sA[BM * BK];  // 8 KiB
  __shared__ uint8_t sB[BN * BK];  // 8 KiB
  const int tid = threadIdx.x;
  const int lane = tid & 63;
  const int wave = tid >> 6;
  const int ntn = N / BN;
  const int tileM = (int)(blockIdx.x / ntn) * BM;
  const int tileN = (int)(blockIdx.x % ntn) * BN;
  const int wm = (wave >> 1) * 64;  // 2x2 waves, each 64x64 output
  const int wn = (wave & 1) * 64;
  const int fr = lane & 15;   // fragment row/col within 16
  const int fq = lane >> 4;   // k-quadrant

  f32x4 acc[4][4] = {};

  // staging map: linear byte o = tid*16 within half-tile; row = o>>6, col = o&63
  const int so = tid * 16;
  const int srow = so >> 6;       // 0..63
  const int scol = so & 63;
  const uint8_t* gA0 = Aq + (size_t)(tileM + srow) * Kd + scol;
  const uint8_t* gA1 = Aq + (size_t)(tileM + srow + 64) * Kd + scol;
  const uint8_t* gB0 = Bq + (size_t)(tileN + srow) * Kd + scol;
  const uint8_t* gB1 = Bq + (size_t)(tileN + srow + 64) * Kd + scol;

  for (int k0 = 0; k0 < Kd; k0 += BK) {
    __syncthreads();  // previous compute done before overwriting LDS
    gload16(gA0 + k0, sA + so);
    gload16(gA1 + k0, sA + so + 4096);
    gload16(gB0 + k0, sB + so);
    gload16(gB1 + k0, sB + so + 4096);
    __syncthreads();  // barrier drains vmcnt -> staged data visible

    long a[2][4], b[2][4];
#pragma unroll
    for (int ks = 0; ks < 2; ++ks) {
#pragma unroll
      for (int mf = 0; mf < 4; ++mf)
        a[ks][mf] =
            *(const long*)(sA + (wm + mf * 16 + fr) * 64 + ks * 32 + fq * 8);
#pragma unroll
      for (int nf = 0; nf < 4; ++nf)
        b[ks][nf] =
            *(const long*)(sB + (wn + nf * 16 + fr) * 64 + ks * 32 + fq * 8);
    }
#pragma unroll
    for (int ks = 0; ks < 2; ++ks)
#pragma unroll
      for (int mf = 0; mf < 4; ++mf)
#pragma unroll
        for (int nf = 0; nf < 4; ++nf)
          acc[mf][nf] = __builtin_amdgcn_mfma_f32_16x16x32_fp8_fp8(
              a[ks][mf], b[ks][nf], acc[mf][nf], 0, 0, 0);
  }

  // epilogue: C/D layout (m89): col = lane&15, row = (lane>>4)*4 + reg
  float bscale[4], bbias[4];
#pragma unroll
  for (int nf = 0; nf < 4; ++nf) {
    int col = tileN + wn + nf * 16 + fr;
    bscale[nf] = Bs[col];
    bbias[nf] = bias[col];
  }
#pragma unroll
  for (int mf = 0; mf < 4; ++mf) {
    int r0 = tileM + wm + mf * 16 + fq * 4;
#pragma unroll
    for (int i = 0; i < 4; ++i) {
      float as = As[r0 + i];
      float* crow = C + (size_t)(r0 + i) * N;
#pragma unroll
      for (int nf = 0; nf < 4; ++nf) {
        int col = tileN + wn + nf * 16 + fr;
        crow[col] = acc[mf][nf][i] * as * bscale[nf] + bbias[nf];
      }
    }
  }
}

// ---------------------------------------------------------------------------

extern "C" void kernel_launch(void* const* d_in, const int* in_sizes, int n_in,
                              void* d_out, int out_size, void* d_ws,
                              size_t ws_size, hipStream_t stream) {
  const float* x = (const float*)d_in[0];     // (B,S,K) fp32
  const float* w = (const float*)d_in[1];     // (N,K) fp32
  const float* bias = (const float*)d_in[2];  // (N,) fp32
  // d_in[3]: hadamard matrix — unused (Sylvester H computed via FWHT)

  const int N = in_sizes[2];             // 1024
  const int Kd = in_sizes[1] / N;        // 1024
  const int M = in_sizes[0] / Kd;        // 32768
  float* out = (float*)d_out;

  uint8_t* xq = (uint8_t*)d_ws;                       // M*K fp8
  uint8_t* wq = xq + (size_t)M * Kd;                  // N*K fp8
  float* xs = (float*)(wq + (size_t)N * Kd);          // M scales
  float* wsc = xs + M;                                // N scales

  hq_quant_kernel<<<2048, 256, 0, stream>>>(x, w, xq, wq, xs, wsc, M, N);

  dim3 grid((M / 128) * (N / 128));
  hq_gemm_kernel<<<grid, 256, 0, stream>>>(xq, wq, xs, wsc, bias, out, M, N,
                                           Kd);
}

// Round 2
// 295.378 us; speedup vs baseline: 1.2157x; 1.2157x over previous
//
#include <hip/hip_runtime.h>
#include <cstdint>

typedef __attribute__((ext_vector_type(4))) float f32x4;

// ---------------------------------------------------------------------------
// Kernel 1: block-64 Hadamard rotate (FWHT) + per-row absmax fp8-e4m3fn quant
// One wave per row (K=1024). Layout: lane holds, for each chunk g (0..3),
// the 4 consecutive floats at col (g<<8)|(lane<<2). I.e. element index within
// a 64-block: i = ((lane&15)<<2)|t, block = (g<<2)|(lane>>4).
//   - FWHT stages on i-bits 0,1: in-lane (pure VALU)
//   - FWHT stages on i-bits 2..5: shfl_xor with lane^1,2,4,8 (same block ok,
//     since lane>>4 untouched)
// Same ascending stage order as the previously-passing kernel => identical
// fp32 rounding tree. All loads dwordx4-coalesced, stores dword-coalesced,
// no LDS.
// ---------------------------------------------------------------------------

#define KDIM 1024

__global__ __launch_bounds__(256) void hq_quant_kernel(
    const float* __restrict__ x, const float* __restrict__ w,
    uint8_t* __restrict__ xq, uint8_t* __restrict__ wq,
    float* __restrict__ xs, float* __restrict__ wsc, int mrows, int nrows) {
  const int lane = threadIdx.x & 63;
  const int gwave = (blockIdx.x * blockDim.x + threadIdx.x) >> 6;
  const int wstride = (gridDim.x * blockDim.x) >> 6;
  const int total = mrows + nrows;

  for (int r = gwave; r < total; r += wstride) {
    const float* src = (r < mrows) ? (x + (size_t)r * KDIM)
                                   : (w + (size_t)(r - mrows) * KDIM);
    uint8_t* dst = (r < mrows) ? (xq + (size_t)r * KDIM)
                               : (wq + (size_t)(r - mrows) * KDIM);
    float* sdst = (r < mrows) ? (xs + r) : (wsc + (r - mrows));

    f32x4 v[4];
    const f32x4* s4 = reinterpret_cast<const f32x4*>(src);
#pragma unroll
    for (int g = 0; g < 4; ++g) v[g] = s4[g * 64 + lane];

    // in-lane stages: i-bit0 (s=1), i-bit1 (s=2)
#pragma unroll
    for (int g = 0; g < 4; ++g) {
      float a0 = v[g][0], a1 = v[g][1], a2 = v[g][2], a3 = v[g][3];
      float b0 = a0 + a1, b1 = a0 - a1, b2 = a2 + a3, b3 = a2 - a3;
      v[g][0] = b0 + b2;
      v[g][1] = b1 + b3;
      v[g][2] = b0 - b2;
      v[g][3] = b1 - b3;
    }
    // cross-lane stages: i-bits 2..5 <-> lane bits 0..3
#pragma unroll
    for (int sl = 1; sl <= 8; sl <<= 1) {
      const bool hi = (lane & sl) != 0;
#pragma unroll
      for (int g = 0; g < 4; ++g)
#pragma unroll
        for (int t = 0; t < 4; ++t) {
          float o = __shfl_xor(v[g][t], sl, 64);
          v[g][t] = hi ? (o - v[g][t]) : (v[g][t] + o);
        }
    }

    float amax = 0.f;
#pragma unroll
    for (int g = 0; g < 4; ++g)
#pragma unroll
      for (int t = 0; t < 4; ++t) {
        v[g][t] *= 0.125f;  // 1/sqrt(64), exact
        amax = fmaxf(amax, fabsf(v[g][t]));
      }
#pragma unroll
    for (int s = 1; s < 64; s <<= 1) amax = fmaxf(amax, __shfl_xor(amax, s, 64));

    const float scale = fmaxf(amax / 448.0f, 1e-12f);  // exact, as reference

#pragma unroll
    for (int g = 0; g < 4; ++g) {
      int p = __builtin_amdgcn_cvt_pk_fp8_f32(v[g][0] / scale, v[g][1] / scale,
                                              0, false);
      p = __builtin_amdgcn_cvt_pk_fp8_f32(v[g][2] / scale, v[g][3] / scale, p,
                                          true);
      reinterpret_cast<uint32_t*>(dst)[g * 64 + lane] = (uint32_t)p;
    }
    if (lane == 0) *sdst = scale;
  }
}

// ---------------------------------------------------------------------------
// Kernel 2: fp8 GEMM  C[M,N] = (Aq[M,K] . Bq[N,K]^T) * as[m] * bs[n] + bias[n]
// 128x128 tile, BK=64, 4 waves (2x2 of 64x64), mfma_f32_16x16x32_fp8_fp8.
// Double-buffered prefetch (stage t+1 before compute t, one barrier/K-step),
// 16B-granularity XOR swizzle (source-side + read-side), XCD-aware block
// swizzle (nwg % 8 == 0 -> simple bijective form).
// ---------------------------------------------------------------------------

__device__ __forceinline__ void gload16(const uint8_t* g, uint8_t* l) {
  __builtin_amdgcn_global_load_lds(
      (const __attribute__((address_space(1))) void*)g,
      (__attribute__((address_space(3))) void*)l, 16, 0, 0);
}

__global__ __launch_bounds__(256) void hq_gemm_kernel(
    const uint8_t* __restrict__ Aq, const uint8_t* __restrict__ Bq,
    const float* __restrict__ As, const float* __restrict__ Bs,
    const float* __restrict__ bias, float* __restrict__ C, int M, int N,
    int Kd) {
  constexpr int BM = 128, BN = 128, BK = 64;
  __shared__ uint8_t sA0[BM * BK], sB0[BN * BK];  // 8 KiB each
  __shared__ uint8_t sA1[BM * BK], sB1[BN * BK];
  const int tid = threadIdx.x;
  const int lane = tid & 63;
  const int wave = tid >> 6;
  const int ntn = N / BN;

  // XCD-aware bijective swizzle (grid multiple of 8)
  const int nwg = gridDim.x;
  const int bid = blockIdx.x;
  const int wg = (bid & 7) * (nwg >> 3) + (bid >> 3);

  const int tileM = (wg / ntn) * BM;
  const int tileN = (wg % ntn) * BN;
  const int wm = (wave >> 1) * 64;  // 2x2 waves, each 64x64 output
  const int wn = (wave & 1) * 64;
  const int fr = lane & 15;  // fragment row/col within 16
  const int fq = lane >> 4;  // k-quadrant

  f32x4 acc[4][4] = {};

  // staging map: LDS chunk (srow, scol) holds global col scol ^ ((srow&3)<<4)
  const int so = tid * 16;
  const int srow = so >> 6;  // 0..63
  const int scol = so & 63;
  const int scsw = scol ^ ((srow & 3) << 4);  // pre-swizzled source col
  const uint8_t* gA0 = Aq + (size_t)(tileM + srow) * Kd + scsw;
  const uint8_t* gA1 = Aq + (size_t)(tileM + srow + 64) * Kd + scsw;
  const uint8_t* gB0 = Bq + (size_t)(tileN + srow) * Kd + scsw;
  const uint8_t* gB1 = Bq + (size_t)(tileN + srow + 64) * Kd + scsw;

  auto stage = [&](uint8_t* dA, uint8_t* dB, int k0) {
    gload16(gA0 + k0, dA + so);
    gload16(gA1 + k0, dA + so + 4096);
    gload16(gB0 + k0, dB + so);
    gload16(gB1 + k0, dB + so + 4096);
  };

  auto compute = [&](const uint8_t* dA, const uint8_t* dB) {
    long a[2][4], b[2][4];
#pragma unroll
    for (int ks = 0; ks < 2; ++ks) {
      const int csw = (ks * 32 + fq * 8) ^ ((fr & 3) << 4);
#pragma unroll
      for (int mf = 0; mf < 4; ++mf)
        a[ks][mf] = *(const long*)(dA + (wm + mf * 16 + fr) * 64 + csw);
#pragma unroll
      for (int nf = 0; nf < 4; ++nf)
        b[ks][nf] = *(const long*)(dB + (wn + nf * 16 + fr) * 64 + csw);
    }
#pragma unroll
    for (int ks = 0; ks < 2; ++ks)
#pragma unroll
      for (int mf = 0; mf < 4; ++mf)
#pragma unroll
        for (int nf = 0; nf < 4; ++nf)
          acc[mf][nf] = __builtin_amdgcn_mfma_f32_16x16x32_fp8_fp8(
              a[ks][mf], b[ks][nf], acc[mf][nf], 0, 0, 0);
  };

  // --- double-buffered main loop (requires Kd/BK even; 1024/64 = 16) ---
  stage(sA0, sB0, 0);
  __syncthreads();  // drain vmcnt(0) + barrier: tile0 visible

  int k0 = 0;
  for (; k0 + 2 * BK < Kd; k0 += 2 * BK) {
    stage(sA1, sB1, k0 + BK);  // prefetch issued before compute
    compute(sA0, sB0);
    __syncthreads();
    stage(sA0, sB0, k0 + 2 * BK);
    compute(sA1, sB1);
    __syncthreads();
  }
  stage(sA1, sB1, k0 + BK);  // last tile
  compute(sA0, sB0);
  __syncthreads();
  compute(sA1, sB1);

  // epilogue: C/D layout (m89): col = lane&15, row = (lane>>4)*4 + reg
  float bscale[4], bbias[4];
#pragma unroll
  for (int nf = 0; nf < 4; ++nf) {
    int col = tileN + wn + nf * 16 + fr;
    bscale[nf] = Bs[col];
    bbias[nf] = bias[col];
  }
#pragma unroll
  for (int mf = 0; mf < 4; ++mf) {
    int r0 = tileM + wm + mf * 16 + fq * 4;
#pragma unroll
    for (int i = 0; i < 4; ++i) {
      float as = As[r0 + i];
      float* crow = C + (size_t)(r0 + i) * N;
#pragma unroll
      for (int nf = 0; nf < 4; ++nf) {
        int col = tileN + wn + nf * 16 + fr;
        crow[col] = acc[mf][nf][i] * as * bscale[nf] + bbias[nf];
      }
    }
  }
}

// ---------------------------------------------------------------------------

extern "C" void kernel_launch(void* const* d_in, const int* in_sizes, int n_in,
                              void* d_out, int out_size, void* d_ws,
                              size_t ws_size, hipStream_t stream) {
  const float* x = (const float*)d_in[0];     // (B,S,K) fp32
  const float* w = (const float*)d_in[1];     // (N,K) fp32
  const float* bias = (const float*)d_in[2];  // (N,) fp32
  // d_in[3]: hadamard matrix — unused (Sylvester H computed via FWHT)

  const int N = in_sizes[2];       // 1024
  const int Kd = in_sizes[1] / N;  // 1024
  const int M = in_sizes[0] / Kd;  // 32768
  float* out = (float*)d_out;

  uint8_t* xq = (uint8_t*)d_ws;               // M*K fp8
  uint8_t* wq = xq + (size_t)M * Kd;          // N*K fp8
  float* xs = (float*)(wq + (size_t)N * Kd);  // M scales
  float* wsc = xs + M;                        // N scales

  hq_quant_kernel<<<2048, 256, 0, stream>>>(x, w, xq, wq, xs, wsc, M, N);

  dim3 grid((M / 128) * (N / 128));
  hq_gemm_kernel<<<grid, 256, 0, stream>>>(xq, wq, xs, wsc, bias, out, M, N,
                                           Kd);
}